// Round 14
// baseline (456.842 us; speedup 1.0000x reference)
//
#include <hip/hip_runtime.h>

#define GQA 4
#define Q_LEN 64
#define SCALE 0.08838834764831845f
#define RLN2 1.4426950408889634f
#define NTILES 66          // 64 cache tiles + 2 new-token tiles of 32 keys
#define CACHE_TILES 64

typedef __attribute__((ext_vector_type(4))) float f4;
typedef __attribute__((ext_vector_type(4))) float f32x4;
typedef __attribute__((ext_vector_type(8))) short short8;
typedef __attribute__((ext_vector_type(4))) unsigned int u32x4;

__device__ __forceinline__ unsigned cvt_pk(float lo, float hi) {
  unsigned r;
  asm("v_cvt_pk_bf16_f32 %0, %1, %2" : "=v"(r) : "v"(lo), "v"(hi));
  return r;
}
__device__ __forceinline__ unsigned short f2bf(float f) {
  unsigned u = __builtin_bit_cast(unsigned, f);
  u += 0x7fffu + ((u >> 16) & 1u);
  return (unsigned short)(u >> 16);
}

// ---- LDS layout (bytes): double-buffered K and V ----
#define KBUF   8192    // per buffer: [32 key][256B] bf16, 16B-slot swizzle
#define V0_OFF 16384   // per buffer: transposed [128 d][stride 80B] bf16
#define VBUF   10240
#define P_OFF  36864   // 4 waves x [16 rows][80B]
#define BT_OFF 41984   // 64 ints
#define LDS_BYTES 42240

__device__ __forceinline__ unsigned k_addr(int key, int d) {
  return (unsigned)(key * 256 + ((d * 2) ^ ((key & 7) << 4)));
}
__device__ __forceinline__ unsigned v_addr(int d, int key) {
  return (unsigned)(d * 80 + key * 2);
}

#define SCHED0() __builtin_amdgcn_sched_barrier(0)
// raw barrier: LDS-visibility wait only; NO memory clobber (a clobber forces
// live register state to scratch — r13's 323MB WRITE_SIZE regression).
// sched_barrier(0) pins ds ops on either side (m201 template pattern).
#define BAR() do { SCHED0(); asm volatile("s_waitcnt lgkmcnt(0)"); SCHED0(); \
                   __builtin_amdgcn_s_barrier(); SCHED0(); } while (0)

// prefetch state: named members, passed BY VALUE (SSA, no address escape)
struct KV { f4 k0, k1, k2, k3, v0, v1, v2, v3; };

// grid = nc*256: bid = c*256 + g*64 + s*8 + h  (GQA/chunk siblings share XCD)
__global__ __launch_bounds__(256, 3)
void attn_partial(const float* __restrict__ q, const float* __restrict__ kn,
                  const float* __restrict__ vn, const float* __restrict__ kc,
                  const float* __restrict__ vc, const int* __restrict__ btab,
                  float* __restrict__ part_o, float* __restrict__ part_ml,
                  float* __restrict__ out, int nc)
{
  __shared__ __align__(16) char lds[LDS_BYTES];
  const int bid  = blockIdx.x;
  const int c    = bid >> 8;
  const int rest = bid & 255;
  const int g = rest >> 6, s = (rest >> 3) & 7, h = rest & 7;
  const int tid  = threadIdx.x;
  const int wave = tid >> 6, lane = tid & 63;
  const int lhi  = lane >> 4, llo = lane & 15;

  const int base  = NTILES / nc, rem = NTILES % nc;
  const int start = c * base + (c < rem ? c : rem);
  const int nt    = base + (c < rem ? 1 : 0);
  const int tlast = start + nt - 1;

  if (tid < 64) *(int*)(lds + BT_OFF + tid * 4) = btab[s * CACHE_TILES + tid];

  // ---- Q fragment (rows wave*16+llo), pre-scaled into exp2 domain ----
  short8 qf[4];
  {
    const float qsc = SCALE * RLN2;
    const float* qrow = q + (size_t)(s * Q_LEN + wave * 16 + llo) * 4096 + (h * GQA + g) * 128;
#pragma unroll
    for (int cc = 0; cc < 4; ++cc) {
      const float* p = qrow + cc * 32 + lhi * 8;
      f4 a = *(const f4*)p; f4 b = *(const f4*)(p + 4);
      u32x4 w;
      w[0] = cvt_pk(a[0] * qsc, a[1] * qsc); w[1] = cvt_pk(a[2] * qsc, a[3] * qsc);
      w[2] = cvt_pk(b[0] * qsc, b[1] * qsc); w[3] = cvt_pk(b[2] * qsc, b[3] * qsc);
      qf[cc] = __builtin_bit_cast(short8, w);
    }
  }

  f32x4 of[8];
#pragma unroll
  for (int i = 0; i < 8; ++i) of[i] = (f32x4){0.f, 0.f, 0.f, 0.f};
  float m_run[4], l_run[4];
#pragma unroll
  for (int r = 0; r < 4; ++r) { m_run[r] = -1e30f; l_run[r] = 0.f; }

  // staging maps (block-wide): K row=tid>>3 cols (tid&7)*16; V d-quad=(tid>>3)*4 key-pair=tid&7(+16)
  const int ktk = tid >> 3;
  const int kc0 = (tid & 7) * 16;
  const int vdq = (tid >> 3) * 4;
  const int vkp = tid & 7;
  const size_t k_toff = (size_t)ktk * 1024 + h * 128 + kc0;
  const size_t v_off0 = (size_t)(2 * vkp) * 1024 + h * 128 + vdq;

  auto load_kv = [&](int tile) -> KV {
    const float *kb_, *vb_;
    if (tile < CACHE_TILES) {
      const int pb = *(const int*)(lds + BT_OFF + tile * 4);
      kb_ = kc + (size_t)pb * 32768;
      vb_ = vc + (size_t)pb * 32768;
    } else {
      const size_t row0 = (size_t)(s * Q_LEN + (tile - CACHE_TILES) * 32) * 1024;
      kb_ = kn + row0;
      vb_ = vn + row0;
    }
    KV t;
    t.k0 = *(const f4*)(kb_ + k_toff);
    t.k1 = *(const f4*)(kb_ + k_toff + 4);
    t.k2 = *(const f4*)(kb_ + k_toff + 8);
    t.k3 = *(const f4*)(kb_ + k_toff + 12);
    t.v0 = *(const f4*)(vb_ + v_off0);            // key 2kp
    t.v1 = *(const f4*)(vb_ + v_off0 + 1024);     // key 2kp+1
    t.v2 = *(const f4*)(vb_ + v_off0 + 16384);    // key 2kp+16
    t.v3 = *(const f4*)(vb_ + v_off0 + 17408);    // key 2kp+17
    return t;
  };
  auto write_kv = [&](int sel, KV t) {            // by value: no address escape
    u32x4 w0, w1;
    w0[0] = cvt_pk(t.k0[0], t.k0[1]); w0[1] = cvt_pk(t.k0[2], t.k0[3]);
    w0[2] = cvt_pk(t.k1[0], t.k1[1]); w0[3] = cvt_pk(t.k1[2], t.k1[3]);
    w1[0] = cvt_pk(t.k2[0], t.k2[1]); w1[1] = cvt_pk(t.k2[2], t.k2[3]);
    w1[2] = cvt_pk(t.k3[0], t.k3[1]); w1[3] = cvt_pk(t.k3[2], t.k3[3]);
    char* kb = lds + sel * KBUF;
    *(u32x4*)(kb + k_addr(ktk, kc0))     = w0;
    *(u32x4*)(kb + k_addr(ktk, kc0 + 8)) = w1;
    char* vb = lds + V0_OFF + sel * VBUF;
#pragma unroll
    for (int i = 0; i < 4; ++i) {
      *(unsigned*)(vb + v_addr(vdq + i, 2 * vkp))      = cvt_pk(t.v0[i], t.v1[i]);
      *(unsigned*)(vb + v_addr(vdq + i, 2 * vkp + 16)) = cvt_pk(t.v2[i], t.v3[i]);
    }
  };
  auto compute = [&](int sel) {
    const char* kb = lds + sel * KBUF;
    const char* vb = lds + V0_OFF + sel * VBUF;
    f32x4 s0 = {0.f,0.f,0.f,0.f}, s1 = {0.f,0.f,0.f,0.f};
    __builtin_amdgcn_s_setprio(1);
#pragma unroll
    for (int cc = 0; cc < 4; ++cc) {
      short8 kf0 = *(const short8*)(kb + k_addr(llo,      cc * 32 + lhi * 8));
      short8 kf1 = *(const short8*)(kb + k_addr(llo + 16, cc * 32 + lhi * 8));
      s0 = __builtin_amdgcn_mfma_f32_16x16x32_bf16(qf[cc], kf0, s0, 0, 0, 0);
      s1 = __builtin_amdgcn_mfma_f32_16x16x32_bf16(qf[cc], kf1, s1, 0, 0, 0);
    }
    __builtin_amdgcn_s_setprio(0);
    float p0[4], p1[4], tred[4];
#pragma unroll
    for (int r = 0; r < 4; ++r) tred[r] = fmaxf(s0[r], s1[r]);
#pragma unroll
    for (int off = 1; off < 16; off <<= 1)
#pragma unroll
      for (int r = 0; r < 4; ++r) tred[r] = fmaxf(tred[r], __shfl_xor(tred[r], off, 64));

    bool grow = (tred[0] > m_run[0]) | (tred[1] > m_run[1]) |
                (tred[2] > m_run[2]) | (tred[3] > m_run[3]);
    const int resc = __any((int)grow);
    float corr[4];
    if (resc) {
#pragma unroll
      for (int r = 0; r < 4; ++r) {
        const float mnew = fmaxf(m_run[r], tred[r]);
        corr[r] = exp2f(m_run[r] - mnew);
        m_run[r] = mnew;
      }
    }
#pragma unroll
    for (int r = 0; r < 4; ++r) {
      p0[r] = exp2f(s0[r] - m_run[r]);
      p1[r] = exp2f(s1[r] - m_run[r]);
      tred[r] = p0[r] + p1[r];
    }
#pragma unroll
    for (int off = 1; off < 16; off <<= 1)
#pragma unroll
      for (int r = 0; r < 4; ++r) tred[r] += __shfl_xor(tred[r], off, 64);
    if (resc) {
#pragma unroll
      for (int r = 0; r < 4; ++r) l_run[r] = l_run[r] * corr[r] + tred[r];
#pragma unroll
      for (int dc = 0; dc < 8; ++dc)
#pragma unroll
        for (int r = 0; r < 4; ++r) of[dc][r] *= corr[r];
    } else {
#pragma unroll
      for (int r = 0; r < 4; ++r) l_run[r] += tred[r];
    }

    // P -> LDS re-layout into A-fragment (per-wave private, no barrier)
    char* pb_ = lds + P_OFF + wave * 1280;
#pragma unroll
    for (int r = 0; r < 4; ++r) {
      const int row = lhi * 4 + r;
      *(unsigned short*)(pb_ + row * 80 + llo * 2)        = f2bf(p0[r]);
      *(unsigned short*)(pb_ + row * 80 + (llo + 16) * 2) = f2bf(p1[r]);
    }
    short8 pa = *(const short8*)(pb_ + llo * 80 + lhi * 16);
    __builtin_amdgcn_s_setprio(1);
#pragma unroll
    for (int dc = 0; dc < 8; ++dc) {
      short8 vf = *(const short8*)(vb + v_addr(dc * 16 + llo, lhi * 8));
      of[dc] = __builtin_amdgcn_mfma_f32_16x16x32_bf16(pa, vf, of[dc], 0, 0, 0);
    }
    __builtin_amdgcn_s_setprio(0);
  };

  auto tclamp = [&](int t) { return t > tlast ? tlast : t; };

  BAR();                                   // block table visible
  // ---- pipeline prologue: depth-2 prefetch, buf0 staged ----
  KV A = load_kv(tclamp(start));
  KV B = load_kv(tclamp(start + 1));
  write_kv(0, A);                          // counted vmcnt waits on A's loads only
  A = load_kv(tclamp(start + 2));
  BAR();                                   // buf0 ready; B + next-A loads in flight

  for (int it = 0; it < nt; it += 2) {
    compute(0);                            // even tile (buf0)
    write_kv(1, B);
    B = load_kv(tclamp(start + it + 3));
    BAR();
    if (it + 1 >= nt) break;
    compute(1);                            // odd tile (buf1)
    write_kv(0, A);
    A = load_kv(tclamp(start + it + 4));
    BAR();
  }

  // ---- epilogue: partials to ws (or direct out when nc==1) ----
  if (nc == 1) {
    float inv[4];
#pragma unroll
    for (int r = 0; r < 4; ++r) inv[r] = 1.f / l_run[r];
#pragma unroll
    for (int dc = 0; dc < 8; ++dc)
#pragma unroll
      for (int r = 0; r < 4; ++r)
        out[(size_t)(s * Q_LEN + wave * 16 + lhi * 4 + r) * 4096
            + (size_t)((h * GQA + g) * 128 + dc * 16 + llo)] = of[dc][r] * inv[r];
  } else {
#pragma unroll
    for (int dc = 0; dc < 8; ++dc)
#pragma unroll
      for (int r = 0; r < 4; ++r) {
        const int row = wave * 16 + lhi * 4 + r;
        part_o[((size_t)bid * 64 + row) * 128 + dc * 16 + llo] = of[dc][r];
      }
    if (llo == 0) {
#pragma unroll
      for (int r = 0; r < 4; ++r) {
        const int row = wave * 16 + lhi * 4 + r;
        part_ml[(size_t)bid * 128 + row]      = m_run[r];
        part_ml[(size_t)bid * 128 + 64 + row] = l_run[r];
      }
    }
  }
}

template<int NC>
__global__ __launch_bounds__(256)
void merge_k(const float* __restrict__ po, const float* __restrict__ pml,
             float* __restrict__ out)
{
  const int t   = blockIdx.x * 256 + threadIdx.x;    // 512*32*32 threads
  const int d4  = t & 31;
  const int hh  = (t >> 5) & 31;
  const int tok = t >> 10;
  const int s = tok >> 6, row = tok & 63, h = hh >> 2, g = hh & 3;

  float m[NC], l[NC]; f4 o[NC];
  float M = -1e30f;
#pragma unroll
  for (int c = 0; c < NC; ++c) {
    const int bid = c * 256 + g * 64 + s * 8 + h;
    m[c] = pml[(size_t)bid * 128 + row];
    l[c] = pml[(size_t)bid * 128 + 64 + row];
    o[c] = *(const f4*)&po[((size_t)bid * 64 + row) * 128 + d4 * 4];
    M = fmaxf(M, m[c]);
  }
  f4 num = {0.f,0.f,0.f,0.f};
  float den = 0.f;
#pragma unroll
  for (int c = 0; c < NC; ++c) {
    const float w = exp2f(m[c] - M);
    num += w * o[c];
    den += w * l[c];
  }
  const float inv = 1.f / den;
  *(f4*)&out[(size_t)tok * 4096 + hh * 128 + d4 * 4] = num * inv;
}

extern "C" void kernel_launch(void* const* d_in, const int* in_sizes, int n_in,
                              void* d_out, int out_size, void* d_ws, size_t ws_size,
                              hipStream_t stream) {
  (void)in_sizes; (void)n_in; (void)out_size;
  const float* q  = (const float*)d_in[0];
  const float* k  = (const float*)d_in[1];
  const float* v  = (const float*)d_in[2];
  const float* kc = (const float*)d_in[3];
  const float* vc = (const float*)d_in[4];
  const int* bt   = (const int*)d_in[5];
  float* out = (float*)d_out;

  const size_t per_chunk = 256ull * 64 * 128 * 4 + 256ull * 128 * 4;  // o + ml per chunk set
  int NC = 1;
  if (ws_size >= 4 * per_chunk) NC = 4;
  else if (ws_size >= 2 * per_chunk) NC = 2;

  float* po  = (float*)d_ws;
  float* pml = po + (size_t)NC * 256 * 64 * 128;

  attn_partial<<<dim3(NC * 256), dim3(256), 0, stream>>>(q, k, v, kc, vc, bt, po, pml, out, NC);
  if (NC == 4)      merge_k<4><<<dim3(2048), dim3(256), 0, stream>>>(po, pml, out);
  else if (NC == 2) merge_k<2><<<dim3(2048), dim3(256), 0, stream>>>(po, pml, out);
}

// Round 15
// 296.536 us; speedup vs baseline: 1.5406x; 1.5406x over previous
//
#include <hip/hip_runtime.h>

#define GQA 4
#define Q_LEN 64
#define SCALE 0.08838834764831845f
#define RLN2 1.4426950408889634f
#define NTILES 66          // 64 cache tiles + 2 new-token tiles of 32 keys
#define CACHE_TILES 64

typedef __attribute__((ext_vector_type(4))) float f4;
typedef __attribute__((ext_vector_type(4))) float f32x4;
typedef __attribute__((ext_vector_type(8))) short short8;
typedef __attribute__((ext_vector_type(4))) unsigned int u32x4;

__device__ __forceinline__ unsigned cvt_pk(float lo, float hi) {
  unsigned r;
  asm("v_cvt_pk_bf16_f32 %0, %1, %2" : "=v"(r) : "v"(lo), "v"(hi));
  return r;
}

// ---- LDS layout (bytes) ----
#define K_OFF  0       // [32 key][256B] bf16, 16B-slot swizzle
#define V_OFF  8192    // transposed [128 d][stride 80B] bf16, keys in PERMUTED slots
#define BT_OFF 18432   // 64 ints
#define LDS_BYTES 18688

__device__ __forceinline__ unsigned k_addr(int key, int d) {
  return (unsigned)(key * 256 + ((d * 2) ^ ((key & 7) << 4)));
}
__device__ __forceinline__ unsigned v_addr(int d, int slot) {
  return (unsigned)(d * 80 + slot * 2);
}
// key->slot permutation so swapped-QK score fragments feed PV's A directly:
// keys {4a..4a+3} -> slots {8a..8a+3}; keys {16+4a..16+4a+3} -> slots {8a+4..8a+7}

// grid = nc*256: bid = c*256 + g*64 + s*8 + h  (GQA/chunk siblings share XCD)
__global__ __launch_bounds__(256, 4)
void attn_partial(const float* __restrict__ q, const float* __restrict__ kn,
                  const float* __restrict__ vn, const float* __restrict__ kc,
                  const float* __restrict__ vc, const int* __restrict__ btab,
                  float* __restrict__ part_o, float* __restrict__ part_ml,
                  float* __restrict__ out, int nc)
{
  __shared__ __align__(16) char lds[LDS_BYTES];
  const int bid  = blockIdx.x;
  const int c    = bid >> 8;
  const int rest = bid & 255;
  const int g = rest >> 6, s = (rest >> 3) & 7, h = rest & 7;
  const int tid  = threadIdx.x;
  const int wave = tid >> 6, lane = tid & 63;
  const int lhi  = lane >> 4, llo = lane & 15;

  const int base  = NTILES / nc, rem = NTILES % nc;
  const int start = c * base + (c < rem ? c : rem);
  const int nt    = base + (c < rem ? 1 : 0);

  if (tid < 64) *(int*)(lds + BT_OFF + tid * 4) = btab[s * CACHE_TILES + tid];

  // ---- Q fragment (q-row = wave*16+llo), pre-scaled into exp2 domain ----
  short8 qf[4];
  {
    const float qsc = SCALE * RLN2;
    const float* qrow = q + (size_t)(s * Q_LEN + wave * 16 + llo) * 4096 + (h * GQA + g) * 128;
#pragma unroll
    for (int cc = 0; cc < 4; ++cc) {
      const float* p = qrow + cc * 32 + lhi * 8;
      f4 a = *(const f4*)p; f4 b = *(const f4*)(p + 4);
      u32x4 w;
      w[0] = cvt_pk(a[0] * qsc, a[1] * qsc); w[1] = cvt_pk(a[2] * qsc, a[3] * qsc);
      w[2] = cvt_pk(b[0] * qsc, b[1] * qsc); w[3] = cvt_pk(b[2] * qsc, b[3] * qsc);
      qf[cc] = __builtin_bit_cast(short8, w);
    }
  }

  f32x4 of[8];
#pragma unroll
  for (int i = 0; i < 8; ++i) of[i] = (f32x4){0.f, 0.f, 0.f, 0.f};
  float m_run = -1e30f, l_run = 0.f;   // softmax state for THIS lane's q-row (llo)

  // staging maps: K row=tid>>3, cols (tid&7)*16; V d-quad=(tid>>3)*4, key-pair=tid&7 (+16)
  const int ktk = tid >> 3;
  const int kc0 = (tid & 7) * 16;
  const int vdq = (tid >> 3) * 4;
  const int vkp = tid & 7;
  const int vslot = (vkp >> 1) * 8 + (vkp & 1) * 2;   // permuted slot for keys 2vkp,2vkp+1
  const size_t k_toff = (size_t)ktk * 1024 + h * 128 + kc0;
  const size_t v_off0 = (size_t)(2 * vkp) * 1024 + h * 128 + vdq;

  f4 rk[4], rv[4];
  auto issue_loads = [&](int tile) {
    const float *kb_, *vb_;
    if (tile < CACHE_TILES) {
      const int pb = *(const int*)(lds + BT_OFF + tile * 4);
      kb_ = kc + (size_t)pb * 32768;
      vb_ = vc + (size_t)pb * 32768;
    } else {
      const size_t row0 = (size_t)(s * Q_LEN + (tile - CACHE_TILES) * 32) * 1024;
      kb_ = kn + row0;
      vb_ = vn + row0;
    }
    rk[0] = *(const f4*)(kb_ + k_toff);
    rk[1] = *(const f4*)(kb_ + k_toff + 4);
    rk[2] = *(const f4*)(kb_ + k_toff + 8);
    rk[3] = *(const f4*)(kb_ + k_toff + 12);
    rv[0] = *(const f4*)(vb_ + v_off0);            // key 2vkp
    rv[1] = *(const f4*)(vb_ + v_off0 + 1024);     // key 2vkp+1
    rv[2] = *(const f4*)(vb_ + v_off0 + 16384);    // key 2vkp+16
    rv[3] = *(const f4*)(vb_ + v_off0 + 17408);    // key 2vkp+17
  };
  auto write_tile = [&]() {
    u32x4 w0, w1;
    w0[0] = cvt_pk(rk[0][0], rk[0][1]); w0[1] = cvt_pk(rk[0][2], rk[0][3]);
    w0[2] = cvt_pk(rk[1][0], rk[1][1]); w0[3] = cvt_pk(rk[1][2], rk[1][3]);
    w1[0] = cvt_pk(rk[2][0], rk[2][1]); w1[1] = cvt_pk(rk[2][2], rk[2][3]);
    w1[2] = cvt_pk(rk[3][0], rk[3][1]); w1[3] = cvt_pk(rk[3][2], rk[3][3]);
    *(u32x4*)(lds + K_OFF + k_addr(ktk, kc0))     = w0;
    *(u32x4*)(lds + K_OFF + k_addr(ktk, kc0 + 8)) = w1;
#pragma unroll
    for (int i = 0; i < 4; ++i) {   // keys 2vkp,2vkp+1 -> slots vslot,vslot+1; +16 -> vslot+4
      *(unsigned*)(lds + V_OFF + v_addr(vdq + i, vslot))     = cvt_pk(rv[0][i], rv[1][i]);
      *(unsigned*)(lds + V_OFF + v_addr(vdq + i, vslot + 4)) = cvt_pk(rv[2][i], rv[3][i]);
    }
  };

  __syncthreads();              // block table visible
  issue_loads(start);
  write_tile();
  __syncthreads();

  for (int it = 0; it < nt; ++it) {
    if (it + 1 < nt) issue_loads(start + it + 1);   // fly during compute

    {
      // ---- swapped QK^T: mfma(K, Q) -> lane holds scores for q-row llo,
      //      keys lhi*4+r (s0) and 16+lhi*4+r (s1)
      f32x4 s0 = {0.f,0.f,0.f,0.f}, s1 = {0.f,0.f,0.f,0.f};
#pragma unroll
      for (int cc = 0; cc < 4; ++cc) {
        short8 kf0 = *(const short8*)(lds + K_OFF + k_addr(llo,      cc * 32 + lhi * 8));
        short8 kf1 = *(const short8*)(lds + K_OFF + k_addr(llo + 16, cc * 32 + lhi * 8));
        s0 = __builtin_amdgcn_mfma_f32_16x16x32_bf16(kf0, qf[cc], s0, 0, 0, 0);
        s1 = __builtin_amdgcn_mfma_f32_16x16x32_bf16(kf1, qf[cc], s1, 0, 0, 0);
      }
      // ---- in-register softmax (row = llo): 7 local max + 2 shuffles
      float mx = fmaxf(fmaxf(fmaxf(s0[0], s0[1]), fmaxf(s0[2], s0[3])),
                       fmaxf(fmaxf(s1[0], s1[1]), fmaxf(s1[2], s1[3])));
      mx = fmaxf(mx, __shfl_xor(mx, 16, 64));
      mx = fmaxf(mx, __shfl_xor(mx, 32, 64));

      const int resc = __any((int)(mx > m_run));
      float corr = 1.f;
      if (resc) {
        const float mnew = fmaxf(m_run, mx);
        corr = exp2f(m_run - mnew);
        m_run = mnew;
      }
      float p0[4], p1[4];
#pragma unroll
      for (int r = 0; r < 4; ++r) {
        p0[r] = exp2f(s0[r] - m_run);
        p1[r] = exp2f(s1[r] - m_run);
      }
      float sum = (p0[0] + p0[1]) + (p0[2] + p0[3]) + (p1[0] + p1[1]) + (p1[2] + p1[3]);
      sum += __shfl_xor(sum, 16, 64);
      sum += __shfl_xor(sum, 32, 64);
      if (resc) {
        l_run = l_run * corr + sum;
        // of rows are q = lhi*4+r; fetch that row's corr (lanes with llo==row hold it)
#pragma unroll
        for (int r = 0; r < 4; ++r) {
          const float cr = __shfl(corr, lhi * 16 + lhi * 4 + r, 64);
#pragma unroll
          for (int dc = 0; dc < 8; ++dc) of[dc][r] *= cr;
        }
      } else {
        l_run += sum;
      }

      // ---- P -> bf16 A-fragment IN REGISTER (keys already in V-slot order)
      u32x4 pw;
      pw[0] = cvt_pk(p0[0], p0[1]);   // slots 8lhi, 8lhi+1
      pw[1] = cvt_pk(p0[2], p0[3]);   // slots 8lhi+2,+3
      pw[2] = cvt_pk(p1[0], p1[1]);   // slots 8lhi+4,+5
      pw[3] = cvt_pk(p1[2], p1[3]);   // slots 8lhi+6,+7
      const short8 pa = __builtin_bit_cast(short8, pw);
#pragma unroll
      for (int dc = 0; dc < 8; ++dc) {
        short8 vf = *(const short8*)(lds + V_OFF + v_addr(dc * 16 + llo, lhi * 8));
        of[dc] = __builtin_amdgcn_mfma_f32_16x16x32_bf16(pa, vf, of[dc], 0, 0, 0);
      }
    }

    __syncthreads();
    if (it + 1 < nt) {
      write_tile();
      __syncthreads();
    }
  }

  // ---- epilogue ----
  if (nc == 1) {
    float inv[4];
#pragma unroll
    for (int r = 0; r < 4; ++r)
      inv[r] = 1.f / __shfl(l_run, lhi * 16 + lhi * 4 + r, 64);
#pragma unroll
    for (int dc = 0; dc < 8; ++dc)
#pragma unroll
      for (int r = 0; r < 4; ++r)
        out[(size_t)(s * Q_LEN + wave * 16 + lhi * 4 + r) * 4096
            + (size_t)((h * GQA + g) * 128 + dc * 16 + llo)] = of[dc][r] * inv[r];
  } else {
#pragma unroll
    for (int dc = 0; dc < 8; ++dc)
#pragma unroll
      for (int r = 0; r < 4; ++r) {
        const int row = wave * 16 + lhi * 4 + r;
        part_o[((size_t)bid * 64 + row) * 128 + dc * 16 + llo] = of[dc][r];
      }
    if (lhi == 0) {                      // lane's q-row = wave*16 + llo
      part_ml[(size_t)bid * 128 + wave * 16 + llo]      = m_run;
      part_ml[(size_t)bid * 128 + 64 + wave * 16 + llo] = l_run;
    }
  }
}

template<int NC>
__global__ __launch_bounds__(256)
void merge_k(const float* __restrict__ po, const float* __restrict__ pml,
             float* __restrict__ out)
{
  const int t   = blockIdx.x * 256 + threadIdx.x;    // 512*32*32 threads
  const int d4  = t & 31;
  const int hh  = (t >> 5) & 31;
  const int tok = t >> 10;
  const int s = tok >> 6, row = tok & 63, h = hh >> 2, g = hh & 3;

  float m[NC], l[NC]; f4 o[NC];
  float M = -1e30f;
#pragma unroll
  for (int c = 0; c < NC; ++c) {
    const int bid = c * 256 + g * 64 + s * 8 + h;
    m[c] = pml[(size_t)bid * 128 + row];
    l[c] = pml[(size_t)bid * 128 + 64 + row];
    o[c] = *(const f4*)&po[((size_t)bid * 64 + row) * 128 + d4 * 4];
    M = fmaxf(M, m[c]);
  }
  f4 num = {0.f,0.f,0.f,0.f};
  float den = 0.f;
#pragma unroll
  for (int c = 0; c < NC; ++c) {
    const float w = exp2f(m[c] - M);
    num += w * o[c];
    den += w * l[c];
  }
  const float inv = 1.f / den;
  *(f4*)&out[(size_t)tok * 4096 + hh * 128 + d4 * 4] = num * inv;
}

extern "C" void kernel_launch(void* const* d_in, const int* in_sizes, int n_in,
                              void* d_out, int out_size, void* d_ws, size_t ws_size,
                              hipStream_t stream) {
  (void)in_sizes; (void)n_in; (void)out_size;
  const float* q  = (const float*)d_in[0];
  const float* k  = (const float*)d_in[1];
  const float* v  = (const float*)d_in[2];
  const float* kc = (const float*)d_in[3];
  const float* vc = (const float*)d_in[4];
  const int* bt   = (const int*)d_in[5];
  float* out = (float*)d_out;

  const size_t per_chunk = 256ull * 64 * 128 * 4 + 256ull * 128 * 4;  // o + ml per chunk set
  int NC = 1;
  if (ws_size >= 4 * per_chunk) NC = 4;
  else if (ws_size >= 2 * per_chunk) NC = 2;

  float* po  = (float*)d_ws;
  float* pml = po + (size_t)NC * 256 * 64 * 128;

  attn_partial<<<dim3(NC * 256), dim3(256), 0, stream>>>(q, k, v, kc, vc, bt, po, pml, out, NC);
  if (NC == 4)      merge_k<4><<<dim3(2048), dim3(256), 0, stream>>>(po, pml, out);
  else if (NC == 2) merge_k<2><<<dim3(2048), dim3(256), 0, stream>>>(po, pml, out);
}